// Round 14
// baseline (833.189 us; speedup 1.0000x reference)
//
#include <hip/hip_runtime.h>
#include <hip/hip_bf16.h>

typedef __bf16 bf16x8 __attribute__((ext_vector_type(8)));
typedef float f32x16 __attribute__((ext_vector_type(16)));
typedef unsigned int u32;
typedef unsigned short u16;

// ws layout (bytes):
//   [0,       524288)  WtP   : bf16 W_enc pack [p=16][ks=32][lane=64][e=8]
//   [524288,  655360)  bias2p: f32 [64][512]
//   [655360,  917504)  logits: f32 [65536]
//   [4M..8M)  probe scratch
#define WS_WT     0
#define WS_BIAS   524288
#define WS_LOGITS 655360
#define WS_P0     4194304
#define WS_P1     5242880
#define WS_P2     6291456
#define WS_P3     7340032

__device__ __forceinline__ u16 f2bf(float f) {
    __bf16 h = (__bf16)f;
    return __builtin_bit_cast(u16, h);
}

__device__ __forceinline__ void gload_lds16(const void* g, void* l) {
    __builtin_amdgcn_global_load_lds(
        (const __attribute__((address_space(1))) u32*)g,
        (__attribute__((address_space(3))) u32*)l, 16, 0, 0);
}

__device__ __forceinline__ bf16x8 cvt8(float4 a, float4 b) {
    bf16x8 r;
    r[0] = (__bf16)a.x; r[1] = (__bf16)a.y; r[2] = (__bf16)a.z; r[3] = (__bf16)a.w;
    r[4] = (__bf16)b.x; r[5] = (__bf16)b.y; r[6] = (__bf16)b.z; r[7] = (__bf16)b.w;
    return r;
}

// ---------------- shared macro bodies ----------------
#define DECL_IDS                                                                  \
    int t = threadIdx.x;                                                          \
    int lane = t & 63;                                                            \
    int w = t >> 6;                                                               \
    int blk = blockIdx.x;                                                         \
    int b = blk >> 3;                                                             \
    int cl = lane & 31;                                                           \
    int hi = lane >> 5;                                                           \
    int rloc = lane & 15;                                                         \
    int parity = (lane >> 4) & 1;                                                 \
    int myswz = rloc & 7;                                                         \
    (void)b; (void)cl; (void)parity; (void)myswz;

#define STAGEA(s_, X_)                                                            \
    {                                                                             \
        size_t base_ = ((size_t)blk * 128 + (s_) * 16) * 2048;                    \
        _Pragma("unroll")                                                         \
        for (int j = 0; j < 8; ++j) {                                             \
            int u_ = t + j * 256;                                                 \
            int r_ = u_ >> 7, c_ = u_ & 127;                                      \
            const char* src_ = (const char*)enc + base_ + (size_t)r_ * 2048       \
                               + ((size_t)(c_ ^ (r_ & 7)) * 16);                  \
            gload_lds16(src_, lds + (X_) + (size_t)u_ * 16);                      \
        }                                                                         \
    }
#define STAGEB(off_, p_, h_)                                                      \
    {                                                                             \
        const char* s_ = (const char*)WtP + (size_t)(p_) * 32768                  \
                         + (h_) * 16384 + t * 16;                                 \
        _Pragma("unroll")                                                         \
        for (int j = 0; j < 4; ++j)                                               \
            gload_lds16(s_ + j * 4096, lds + (off_) + t * 16 + j * 4096);         \
    }
#define REDIST(X_)                                                                \
    {                                                                             \
        _Pragma("unroll")                                                         \
        for (int f = 0; f < 32; ++f) {                                            \
            int c0 = (f * 4 + hi * 2) ^ myswz;                                    \
            int c1 = (f * 4 + hi * 2 + 1) ^ myswz;                                \
            float4 lo = *(const float4*)(lds + (X_) + rloc * 2048 + c0 * 16);     \
            float4 h4 = *(const float4*)(lds + (X_) + rloc * 2048 + c1 * 16);     \
            A[f] = cvt8(lo, h4);                                                  \
        }                                                                         \
    }
#define MFMA_PHASE(sl_)                                                           \
    f32x16 acc0 = {}, acc1 = {};                                                  \
    _Pragma("unroll")                                                             \
    for (int i = 0; i < 16; ++i) {                                                \
        uint4 b0 = *(const uint4*)(lds + (sl_) + i * 1024 + lane * 16);           \
        uint4 b1 = *(const uint4*)(lds + (sl_) + 16384 + i * 1024 + lane * 16);   \
        acc0 = __builtin_amdgcn_mfma_f32_32x32x16_bf16(                           \
            A[i], __builtin_bit_cast(bf16x8, b0), acc0, 0, 0, 0);                 \
        acc1 = __builtin_amdgcn_mfma_f32_32x32x16_bf16(                           \
            A[16 + i], __builtin_bit_cast(bf16x8, b1), acc1, 0, 0, 0);            \
    }                                                                             \
    _Pragma("unroll")                                                             \
    for (int r = 0; r < 16; ++r) {                                                \
        float v = acc0[r] + acc1[r] + 0.125f;                                     \
        v = v > 0.f ? v : 0.f;                                                    \
        pr[r] += v * 0.5f;                                                        \
    }

#define SYNTH_A                                                                   \
    bf16x8 A[32];                                                                 \
    {                                                                             \
        uint4 pat;                                                                \
        pat.x = 0x3F803F80u; pat.y = 0x3F003F00u;                                 \
        pat.z = 0x3F803F00u; pat.w = 0x3F003F80u;                                 \
        _Pragma("unroll")                                                         \
        for (int f = 0; f < 32; ++f) A[f] = __builtin_bit_cast(bf16x8, pat);      \
    }                                                                             \
    _Pragma("unroll")                                                             \
    for (int f = 0; f < 32; ++f) asm volatile("" : "+v"(A[f]));

#define STORE_PR(dst_)                                                            \
    {                                                                             \
        float cs = 0.f;                                                           \
        _Pragma("unroll")                                                         \
        for (int r = 0; r < 16; ++r) cs += pr[r];                                 \
        ((float*)(dst_))[blk * 256 + t] = cs;                                     \
    }

// K0a: pack W_enc (R10-verified)
__global__ void k_wt(const float* __restrict__ W, u16* __restrict__ WtP) {
    int u = blockIdx.x * 256 + threadIdx.x;
    int l = u & 63, ks = (u >> 6) & 31, p = u >> 11;
    int n = p * 32 + (l & 31);
    int k0 = ks * 16 + (l >> 5) * 8;
    u16 o[8];
    #pragma unroll
    for (int e = 0; e < 8; ++e)
        o[e] = f2bf(W[(k0 + e) * 512 + n]);
    *(uint4*)(WtP + (size_t)u * 8) = *(const uint4*)o;
}

// K0b: bias2p; blocks 0..63 zero out[0..32768)
__global__ void k_bias2(const float* __restrict__ dec, const float* __restrict__ Wd,
                        const float* __restrict__ b_dec, const float* __restrict__ b_enc,
                        float* __restrict__ bias2p, float* __restrict__ out0) {
    int blk = blockIdx.x;
    int b = blk >> 2, nc = blk & 3;
    int t = threadIdx.x;
    if (blk < 64) {
        out0[blk * 512 + t * 2] = 0.f;
        out0[blk * 512 + t * 2 + 1] = 0.f;
    }
    __shared__ float sdec[512];
    __shared__ float red[256];
    for (int k = t; k < 512; k += 256) sdec[k] = dec[b * 512 + k];
    __syncthreads();
    int n = nc * 128 + (t & 127);
    int kh = t >> 7;
    float acc = 0.f;
    int k0 = kh * 256;
    #pragma unroll 4
    for (int k = k0; k < k0 + 256; ++k)
        acc += sdec[k] * Wd[k * 512 + n];
    red[t] = acc;
    __syncthreads();
    if (t < 128) {
        int nn = nc * 128 + t;
        bias2p[b * 512 + nn] = red[t] + red[t + 128] + b_dec[nn] + b_enc[nn];
    }
}

// ---------------- PROBES (x8 amplified) ----------------
// P0: sync + 2-chain MFMA + epilog only (B from fixed LDS, staged never -> read
// whatever; values irrelevant). Isolation: no VMEM at all in loop.
__global__ __launch_bounds__(256, 2) void p0_mfma(float* __restrict__ scratch) {
    __shared__ __align__(16) char lds[65536];
    DECL_IDS
    ((volatile float*)lds)[t] = 1.0f;   // keep LDS allocated
    __syncthreads();
    SYNTH_A
    float pr[16];
    #pragma unroll
    for (int r = 0; r < 16; ++r) pr[r] = 0.f;
    #pragma unroll 1
    for (int rep = 0; rep < 8; ++rep) {
        #pragma unroll 1
        for (int p = 0; p < 16; ++p) {
            __syncthreads();
            MFMA_PHASE(0)
        }
    }
    STORE_PR(scratch)
}

// P1: A-prologue only, x8
__global__ __launch_bounds__(256, 2) void p1_prologue(const float* __restrict__ enc,
                                                      float* __restrict__ scratch) {
    __shared__ __align__(16) char lds[65536];
    DECL_IDS
    float cs = 0.f;
    #pragma unroll 1
    for (int rep = 0; rep < 8; ++rep) {
        bf16x8 A[32];
        STAGEA(0, 0)
        #pragma unroll 1
        for (int s = 0; s < 8; ++s) {
            __syncthreads();
            if (s < 7) STAGEA(s + 1, ((s + 1) & 1) * 32768)
            if ((s >> 1) == w && (s & 1) == parity) REDIST((s & 1) * 32768)
        }
        __syncthreads();
        #pragma unroll
        for (int f = 0; f < 32; ++f)
            asm volatile("" : "+v"(A[f]));
        #pragma unroll
        for (int f = 0; f < 32; ++f)
            cs += (float)A[f][0];
    }
    scratch[blk * 256 + t] = cs;
}

// P2: exact R13 main loop (ring-4 staging + ds_read + MFMA), x8
__global__ __launch_bounds__(256, 2) void p2_mainloop(const u16* __restrict__ WtP,
                                                      float* __restrict__ scratch) {
    __shared__ __align__(16) char lds[65536];
    DECL_IDS
    SYNTH_A
    float pr[16];
    #pragma unroll
    for (int r = 0; r < 16; ++r) pr[r] = 0.f;
    #pragma unroll 1
    for (int rep = 0; rep < 8; ++rep) {
        STAGEB(0, 0, 0)
        STAGEB(16384, 0, 1)
        #pragma unroll 1
        for (int p = 0; p < 16; ++p) {
            __syncthreads();
            int sl = (p & 1) * 32768;
            int nsl = sl ^ 32768;
            if (p < 15) {
                STAGEB(nsl, p + 1, 0)
                STAGEB(nsl + 16384, p + 1, 1)
            }
            MFMA_PHASE(sl)
        }
    }
    STORE_PR(scratch)
}

// P3: P2 minus staging: B staged once, phases re-read fixed 32KB. x8
__global__ __launch_bounds__(256, 2) void p3_ldsloop(const u16* __restrict__ WtP,
                                                     float* __restrict__ scratch) {
    __shared__ __align__(16) char lds[65536];
    DECL_IDS
    SYNTH_A
    STAGEB(0, 0, 0)
    STAGEB(16384, 0, 1)
    __syncthreads();
    float pr[16];
    #pragma unroll
    for (int r = 0; r < 16; ++r) pr[r] = 0.f;
    #pragma unroll 1
    for (int rep = 0; rep < 8; ++rep) {
        #pragma unroll 1
        for (int p = 0; p < 16; ++p) {
            __syncthreads();
            MFMA_PHASE(0)
        }
    }
    STORE_PR(scratch)
}

// ---------------- real pipeline (R13) ----------------
__global__ __launch_bounds__(256, 2) void k_logits(
        const float* __restrict__ enc, const u16* __restrict__ WtP,
        const float* __restrict__ bias2p, const float* __restrict__ Wf,
        float* __restrict__ logits) {
    __shared__ __align__(16) char lds[65536];
    DECL_IDS

    STAGEA(0, 0)
    bf16x8 A[32];
    for (int s = 0; s < 8; ++s) {
        __syncthreads();
        if (s < 7) STAGEA(s + 1, ((s + 1) & 1) * 32768)
        if ((s >> 1) == w && (s & 1) == parity) REDIST((s & 1) * 32768)
    }
    __syncthreads();
    #pragma unroll
    for (int f = 0; f < 32; ++f)
        asm volatile("" : "+v"(A[f]));

    STAGEB(0, 0, 0)
    STAGEB(16384, 0, 1)

    float pr[16];
    #pragma unroll
    for (int r = 0; r < 16; ++r) pr[r] = 0.f;

    for (int p = 0; p < 16; ++p) {
        __syncthreads();
        int sl = (p & 1) * 32768;
        int nsl = sl ^ 32768;
        if (p < 15) {
            STAGEB(nsl, p + 1, 0)
            STAGEB(nsl + 16384, p + 1, 1)
        }
        f32x16 acc0 = {}, acc1 = {};
        #pragma unroll
        for (int i = 0; i < 16; ++i) {
            uint4 b0 = *(const uint4*)(lds + sl + i * 1024 + lane * 16);
            uint4 b1 = *(const uint4*)(lds + sl + 16384 + i * 1024 + lane * 16);
            acc0 = __builtin_amdgcn_mfma_f32_32x32x16_bf16(
                A[i], __builtin_bit_cast(bf16x8, b0), acc0, 0, 0, 0);
            acc1 = __builtin_amdgcn_mfma_f32_32x32x16_bf16(
                A[16 + i], __builtin_bit_cast(bf16x8, b1), acc1, 0, 0, 0);
        }
        int col = p * 32 + cl;
        float bias = bias2p[b * 512 + col];
        float wfv = Wf[col];
        #pragma unroll
        for (int r = 0; r < 16; ++r) {
            float v = acc0[r] + acc1[r] + bias;
            v = v > 0.f ? v : 0.f;
            pr[r] += v * wfv;
        }
    }

    #pragma unroll
    for (int r = 0; r < 16; ++r) {
        float v = pr[r];
        v += __shfl_xor(v, 1, 64);
        v += __shfl_xor(v, 2, 64);
        v += __shfl_xor(v, 4, 64);
        v += __shfl_xor(v, 8, 64);
        v += __shfl_xor(v, 16, 64);
        if (cl == 0)
            logits[blk * 128 + w * 32 + (r & 3) + 8 * (r >> 2) + 4 * hi] = v;
    }
}

__global__ void k_softmax(const float* __restrict__ logits, float* __restrict__ alpha) {
    int b = blockIdx.x;
    int t = threadIdx.x;
    __shared__ float red[256];
    float4 v = ((const float4*)(logits + b * 1024))[t];
    float mx = fmaxf(fmaxf(v.x, v.y), fmaxf(v.z, v.w));
    red[t] = mx;
    __syncthreads();
    for (int s = 128; s > 0; s >>= 1) {
        if (t < s) red[t] = fmaxf(red[t], red[t + s]);
        __syncthreads();
    }
    mx = red[0];
    __syncthreads();
    float4 e;
    e.x = expf(v.x - mx); e.y = expf(v.y - mx);
    e.z = expf(v.z - mx); e.w = expf(v.w - mx);
    red[t] = e.x + e.y + e.z + e.w;
    __syncthreads();
    for (int s = 128; s > 0; s >>= 1) {
        if (t < s) red[t] += red[t + s];
        __syncthreads();
    }
    float inv = 1.0f / red[0];
    float4 o;
    o.x = e.x * inv; o.y = e.y * inv; o.z = e.z * inv; o.w = e.w * inv;
    ((float4*)(alpha + b * 1024))[t] = o;
}

__global__ void k_wsum_part(const float* __restrict__ enc, const float* __restrict__ alpha,
                            float* __restrict__ out) {
    int blk = blockIdx.x;
    int b = blk >> 3, c = blk & 7;
    int t = threadIdx.x;
    int col = (t & 127) * 4;
    int lh = t >> 7;
    const float* ep = enc + (size_t)(b * 1024 + c * 128) * 512;
    const float* al = alpha + b * 1024 + c * 128;
    float4 s = {0.f, 0.f, 0.f, 0.f};
    #pragma unroll 4
    for (int i = 0; i < 64; ++i) {
        int l = i * 2 + lh;
        float a = al[l];
        float4 e = *(const float4*)(ep + (size_t)l * 512 + col);
        s.x += e.x * a; s.y += e.y * a; s.z += e.z * a; s.w += e.w * a;
    }
    __shared__ float red[2][512];
    *(float4*)&red[lh][col] = s;
    __syncthreads();
    if (t < 128) {
        float4 a0 = *(const float4*)&red[0][t * 4];
        float4 a1 = *(const float4*)&red[1][t * 4];
        float* op = out + b * 512 + t * 4;
        atomicAdd(op + 0, a0.x + a1.x);
        atomicAdd(op + 1, a0.y + a1.y);
        atomicAdd(op + 2, a0.z + a1.z);
        atomicAdd(op + 3, a0.w + a1.w);
    }
}

extern "C" void kernel_launch(void* const* d_in, const int* in_sizes, int n_in,
                              void* d_out, int out_size, void* d_ws, size_t ws_size,
                              hipStream_t stream) {
    const float* enc    = (const float*)d_in[0];
    const float* dec    = (const float*)d_in[1];
    const float* W_enc  = (const float*)d_in[2];
    const float* b_enc  = (const float*)d_in[3];
    const float* W_dec  = (const float*)d_in[4];
    const float* b_dec  = (const float*)d_in[5];
    const float* W_full = (const float*)d_in[6];
    // d_in[7] = b_full: unused (softmax shift-invariant)

    float* out = (float*)d_out;
    char* ws = (char*)d_ws;
    u16* WtP      = (u16*)(ws + WS_WT);
    float* bias2p = (float*)(ws + WS_BIAS);
    float* logits = (float*)(ws + WS_LOGITS);
    float* alpha  = out + 32768;

    hipLaunchKernelGGL(k_wt,        dim3(128), dim3(256), 0, stream, W_enc, WtP);
    hipLaunchKernelGGL(k_bias2,     dim3(256), dim3(256), 0, stream,
                       dec, W_dec, b_dec, b_enc, bias2p, out);
    // ---- probes (diagnostic; outputs to dead scratch) ----
    hipLaunchKernelGGL(p0_mfma,     dim3(512), dim3(256), 0, stream, (float*)(ws + WS_P0));
    hipLaunchKernelGGL(p1_prologue, dim3(512), dim3(256), 0, stream, enc, (float*)(ws + WS_P1));
    hipLaunchKernelGGL(p2_mainloop, dim3(512), dim3(256), 0, stream, WtP, (float*)(ws + WS_P2));
    hipLaunchKernelGGL(p3_ldsloop,  dim3(512), dim3(256), 0, stream, WtP, (float*)(ws + WS_P3));
    // ---- real pipeline ----
    hipLaunchKernelGGL(k_logits,    dim3(512), dim3(256), 0, stream,
                       enc, WtP, bias2p, W_full, logits);
    hipLaunchKernelGGL(k_softmax,   dim3(64),  dim3(256), 0, stream, logits, alpha);
    hipLaunchKernelGGL(k_wsum_part, dim3(512), dim3(256), 0, stream, enc, alpha, out);
}